// Round 1
// 2373.617 us; speedup vs baseline: 1.5820x; 1.5820x over previous
//
#include <hip/hip_runtime.h>
#include <hip/hip_bf16.h>
#include <stdint.h>

#define B_ 64
#define S_ 512
#define I_ 256
#define H_ 512

typedef __attribute__((ext_vector_type(8))) short bf16x8;
typedef __attribute__((ext_vector_type(4))) float f32x4;

__device__ __forceinline__ ushort f2bf(float f) {
  union { float f; uint32_t u; } c; c.f = f;
  uint32_t u = c.u + 0x7FFFu + ((c.u >> 16) & 1u);
  return (ushort)(u >> 16);
}
__device__ __forceinline__ float bf2f(ushort s) {
  union { uint32_t u; float f; } c; c.u = ((uint32_t)s) << 16; return c.f;
}

// ---------------- convert kernels ----------------
__global__ __launch_bounds__(256) void conv_inputs(const float* __restrict__ x,
                                                   ushort* __restrict__ y) {
  int i = blockIdx.x * 256 + threadIdx.x;  // 2,097,152 float4 groups
  float4 v = ((const float4*)x)[i];
  ushort4 o;
  o.x = f2bf(v.x); o.y = f2bf(v.y); o.z = f2bf(v.z); o.w = f2bf(v.w);
  ((ushort4*)y)[i] = o;
}

__global__ __launch_bounds__(256) void conv_w(const float* __restrict__ a,
                                              const float* __restrict__ b,
                                              const float* __restrict__ c,
                                              ushort* __restrict__ y) {
  int i = blockIdx.x * 256 + threadIdx.x;  // 98,304 groups of 4
  int e = i * 4;
  int g = e >> 17;           // 131072 elems per matrix
  int rem = e & 131071;
  const float* src = (g == 0) ? a : (g == 1) ? b : c;
  float4 v = *(const float4*)(src + rem);
  ushort4 o;
  o.x = f2bf(v.x); o.y = f2bf(v.y); o.z = f2bf(v.z); o.w = f2bf(v.w);
  *(ushort4*)(y + e) = o;
}

// ---------------- input-projection GEMM ----------------
// C[m,n] = sum_k A[m,k]*Bw[n,k] + bias;  m = b*512+s (32768), n = g*512+h (1536), K=256
// output layout gi[s][g][b][h] (bf16) for streaming consumption by the scan.
__global__ __launch_bounds__(256) void gemm_gi(const ushort* __restrict__ A,
                                               const ushort* __restrict__ Bw,
                                               const float* __restrict__ b_ir,
                                               const float* __restrict__ b_iz,
                                               const float* __restrict__ b_in,
                                               ushort* __restrict__ gi) {
  __shared__ ushort As[128][40];  // +8 pad: 16B-aligned rows, decorrelated banks
  __shared__ ushort Bs[128][40];
  const int m0 = blockIdx.x * 128;
  const int n0 = blockIdx.y * 128;
  const int tid = threadIdx.x;
  const int lane = tid & 63, wid = tid >> 6;
  const int wm = wid & 1, wn = wid >> 1;
  f32x4 acc[4][4];
  const f32x4 zz = {0.f, 0.f, 0.f, 0.f};
#pragma unroll
  for (int mi = 0; mi < 4; mi++)
#pragma unroll
    for (int ni = 0; ni < 4; ni++) acc[mi][ni] = zz;

  const int r = tid >> 2;
  const int ccol = (tid & 3) * 8;
  for (int kk = 0; kk < 256; kk += 32) {
    __syncthreads();
    *(uint4*)&As[r][ccol]      = *(const uint4*)&A[(size_t)(m0 + r) * 256 + kk + ccol];
    *(uint4*)&As[r + 64][ccol] = *(const uint4*)&A[(size_t)(m0 + r + 64) * 256 + kk + ccol];
    *(uint4*)&Bs[r][ccol]      = *(const uint4*)&Bw[(size_t)(n0 + r) * 256 + kk + ccol];
    *(uint4*)&Bs[r + 64][ccol] = *(const uint4*)&Bw[(size_t)(n0 + r + 64) * 256 + kk + ccol];
    __syncthreads();
    const int q8 = (lane >> 4) * 8;
    bf16x8 af[4], bf[4];
#pragma unroll
    for (int mi = 0; mi < 4; mi++)
      af[mi] = *(const bf16x8*)&As[wm * 64 + mi * 16 + (lane & 15)][q8];
#pragma unroll
    for (int ni = 0; ni < 4; ni++)
      bf[ni] = *(const bf16x8*)&Bs[wn * 64 + ni * 16 + (lane & 15)][q8];
#pragma unroll
    for (int mi = 0; mi < 4; mi++)
#pragma unroll
      for (int ni = 0; ni < 4; ni++)
        acc[mi][ni] = __builtin_amdgcn_mfma_f32_16x16x32_bf16(af[mi], bf[ni], acc[mi][ni], 0, 0, 0);
  }
#pragma unroll
  for (int ni = 0; ni < 4; ni++) {
    int n = n0 + wn * 64 + ni * 16 + (lane & 15);
    int g = n >> 9, hh = n & 511;
    const float* bp = (g == 0) ? b_ir : (g == 1) ? b_iz : b_in;
    float bias = bp[hh];
#pragma unroll
    for (int mi = 0; mi < 4; mi++) {
      int mb = m0 + wm * 64 + mi * 16 + ((lane >> 4) << 2);
#pragma unroll
      for (int v = 0; v < 4; v++) {
        int m = mb + v;
        int s = m & 511, b = m >> 9;
        size_t idx = (((size_t)s * 3 + g) * 64 + b) * 512 + hh;
        gi[idx] = f2bf(acc[mi][ni][v] + bias);
      }
    }
  }
}

// ---------------- persistent scan ----------------
#define CPG 16  // workgroups per batch-group
#define HS 32   // H columns per workgroup

// Cross-WG barrier WITHOUT buffer_wbl2. All cross-WG data (hbuf) is written
// with agent-scope relaxed atomic stores (write-through to the coherence
// point), so the release side only needs vmcnt(0) + s_barrier, and the
// acquire side only needs an acquire fence (waitcnt + buffer_inv, no wbl2).
__device__ __forceinline__ void fast_barrier(int* cnt, int expected) {
  asm volatile("s_waitcnt vmcnt(0)" ::: "memory");  // drain this wave's stores (agent stores now IF-visible)
  __syncthreads();                                  // every wave drains before arriving
  if (threadIdx.x == 0) {
    __hip_atomic_fetch_add(cnt, 1, __ATOMIC_RELAXED, __HIP_MEMORY_SCOPE_AGENT);
    while (__hip_atomic_load(cnt, __ATOMIC_RELAXED, __HIP_MEMORY_SCOPE_AGENT) < expected)
      __builtin_amdgcn_s_sleep(1);
    __builtin_amdgcn_fence(__ATOMIC_ACQUIRE, "agent");  // waitcnt + buffer_inv (no wbl2)
  }
  __syncthreads();
}

__global__ __launch_bounds__(512, 2) void gru_scan(
    const float* __restrict__ h0p, const float* __restrict__ w_hr,
    const float* __restrict__ w_hz, const float* __restrict__ w_hn,
    const float* __restrict__ b_hr, const float* __restrict__ b_hz,
    const float* __restrict__ b_hn, const ushort* __restrict__ gi,
    ushort* __restrict__ hbuf, int* __restrict__ counters, float* __restrict__ out) {
  const int bid = blockIdx.x;
  const int group = bid >> 4, cc = bid & 15;
  const int b0 = group * 16;
  const int hc0 = cc * HS;
  const int tid = threadIdx.x, lane = tid & 63, wid = tid >> 6;
  int* cnt = counters + group * 520;

  __shared__ float atile[3][16][HS + 1];
  __shared__ float hp[16][HS];  // own-slice h state, fp32
  __shared__ float bh[3][HS];

  const size_t BH = (size_t)B_ * H_;

  if (tid < 3 * HS) {
    int g = tid >> 5, n = tid & 31;
    const float* bp = (g == 0) ? b_hr : (g == 1) ? b_hz : b_hn;
    bh[g][n] = bp[hc0 + n];
  }
  {
    int m = tid >> 5, n = tid & 31;
    float v = h0p[(b0 + m) * H_ + hc0 + n];
    hp[m][n] = v;
    // buf[1] is read at t=0 — write-through agent store (visible without wbl2)
    __hip_atomic_store(&hbuf[BH + (b0 + m) * H_ + hc0 + n], f2bf(v),
                       __ATOMIC_RELAXED, __HIP_MEMORY_SCOPE_AGENT);
  }
  // Recurrent-weight B-fragments, resident in VGPRs for the whole kernel.
  // Wave w<3 = gate w, columns hc0 + j*16 + (lane&15), j=0,1; k = ks*32 + (lane>>4)*8 + [0..7]
  bf16x8 bfrag[2][16];
  if (wid < 3) {
    const float* W = (wid == 0) ? w_hr : (wid == 1) ? w_hz : w_hn;
#pragma unroll
    for (int j = 0; j < 2; j++) {
      int row = hc0 + j * 16 + (lane & 15);
      const float* Wr = W + (size_t)row * H_ + ((lane >> 4) << 3);
#pragma unroll
      for (int ks = 0; ks < 16; ks++) {
        const float4 x = *(const float4*)(Wr + ks * 32);
        const float4 y = *(const float4*)(Wr + ks * 32 + 4);
        bf16x8 f;
        f[0] = (short)f2bf(x.x); f[1] = (short)f2bf(x.y);
        f[2] = (short)f2bf(x.z); f[3] = (short)f2bf(x.w);
        f[4] = (short)f2bf(y.x); f[5] = (short)f2bf(y.y);
        f[6] = (short)f2bf(y.z); f[7] = (short)f2bf(y.w);
        bfrag[j][ks] = f;
      }
    }
  }

  const int gm = tid >> 5, gn = tid & 31;
  const size_t goff = (size_t)(b0 + gm) * H_ + hc0 + gn;

  // gi for t=0 — issued before the init barrier so latency hides under it
  ushort cr = gi[goff];
  ushort cz = gi[goff + BH];
  ushort cn = gi[goff + 2 * BH];

  fast_barrier(cnt + 512, CPG);  // h0 visible to whole group

  for (int t = 0; t < S_; t++) {
    // prefetch gi for NEXT step — lives in flight across the raw mid-step
    // barrier (no vmcnt drain there), giving it a full step of cover.
    {
      int tn = (t + 1 < S_) ? t + 1 : t;
      size_t nb = (size_t)tn * 3 * BH + goff;
      ushort nr = gi[nb];
      ushort nz = gi[nb + BH];
      ushort nn = gi[nb + 2 * BH];

      const ushort* hsrc = hbuf + ((t + 1) & 1) * BH + b0 * H_;
      if (wid < 3) {
        const ushort* hb = hsrc + (lane & 15) * H_ + ((lane >> 4) << 3);
        f32x4 acc0 = {0.f, 0.f, 0.f, 0.f}, acc1 = {0.f, 0.f, 0.f, 0.f};
#pragma unroll
        for (int half = 0; half < 2; half++) {
          bf16x8 a[8];
#pragma unroll
          for (int ks = 0; ks < 8; ks++) a[ks] = *(const bf16x8*)(hb + half * 256 + ks * 32);
#pragma unroll
          for (int ks = 0; ks < 8; ks++) {
            acc0 = __builtin_amdgcn_mfma_f32_16x16x32_bf16(a[ks], bfrag[0][half * 8 + ks], acc0, 0, 0, 0);
            acc1 = __builtin_amdgcn_mfma_f32_16x16x32_bf16(a[ks], bfrag[1][half * 8 + ks], acc1, 0, 0, 0);
          }
        }
        const int rr = (lane >> 4) << 2, nn0 = lane & 15;
#pragma unroll
        for (int v = 0; v < 4; v++) {
          atile[wid][rr + v][nn0] = acc0[v];
          atile[wid][rr + v][16 + nn0] = acc1[v];
        }
      }
      // atile hand-off is LDS-only: raw barrier with lgkmcnt drain, so the
      // gi prefetch loads (vmcnt) stay in flight across it.
      asm volatile("s_waitcnt lgkmcnt(0)" ::: "memory");
      __builtin_amdgcn_s_barrier();
      {
        float ar = atile[0][gm][gn], az = atile[1][gm][gn], an = atile[2][gm][gn];
        float hprev = hp[gm][gn];
        float r = 1.f / (1.f + __expf(-(bf2f(cr) + ar + bh[0][gn])));
        float z = 1.f / (1.f + __expf(-(bf2f(cz) + az + bh[1][gn])));
        float narg = bf2f(cn) + r * (an + bh[2][gn]);
        float nv = 2.f / (1.f + __expf(-2.f * narg)) - 1.f;
        float hnew = (1.f - z) * nv + z * hprev;
        hp[gm][gn] = hnew;
        out[((size_t)(b0 + gm) * S_ + t) * H_ + hc0 + gn] = hnew;
        // write-through agent store: IF-visible once vmcnt drains (no wbl2)
        __hip_atomic_store(&hbuf[(t & 1) * BH + (b0 + gm) * H_ + hc0 + gn], f2bf(hnew),
                           __ATOMIC_RELAXED, __HIP_MEMORY_SCOPE_AGENT);
        if (t == S_ - 1) out[(size_t)B_ * S_ * H_ + (b0 + gm) * H_ + hc0 + gn] = hnew;
      }
      cr = nr; cz = nz; cn = nn;
    }
    fast_barrier(cnt + t, CPG);
  }
}

// ---------------- launcher ----------------
extern "C" void kernel_launch(void* const* d_in, const int* in_sizes, int n_in,
                              void* d_out, int out_size, void* d_ws, size_t ws_size,
                              hipStream_t stream) {
  const float* inputs = (const float*)d_in[0];
  const float* hid    = (const float*)d_in[1];
  const float* w_ir   = (const float*)d_in[2];
  const float* w_iz   = (const float*)d_in[3];
  const float* w_in   = (const float*)d_in[4];
  const float* b_ir   = (const float*)d_in[5];
  const float* b_iz   = (const float*)d_in[6];
  const float* b_in   = (const float*)d_in[7];
  const float* w_hr   = (const float*)d_in[8];
  const float* w_hz   = (const float*)d_in[9];
  const float* w_hn   = (const float*)d_in[10];
  const float* b_hr   = (const float*)d_in[11];
  const float* b_hz   = (const float*)d_in[12];
  const float* b_hn   = (const float*)d_in[13];
  float* out = (float*)d_out;

  char* ws = (char*)d_ws;
  ushort* wsA  = (ushort*)(ws);                // inputs bf16: 16,777,216 B
  ushort* wsW  = (ushort*)(ws + 16777216);     // W_i bf16:      786,432 B
  ushort* wsGi = (ushort*)(ws + 17563648);     // gi bf16:   100,663,296 B
  ushort* wsH  = (ushort*)(ws + 118226944);    // h ping-pong:   131,072 B
  int*    wsC  = (int*)(ws + 118358016);       // barriers:        8,320 B

  hipMemsetAsync(wsC, 0, 4 * 520 * 4, stream);
  conv_inputs<<<8192, 256, 0, stream>>>(inputs, wsA);
  conv_w<<<384, 256, 0, stream>>>(w_ir, w_iz, w_in, wsW);
  gemm_gi<<<dim3(256, 12), 256, 0, stream>>>(wsA, wsW, b_ir, b_iz, b_in, wsGi);
  gru_scan<<<64, 512, 0, stream>>>(hid, w_hr, w_hz, w_hn, b_hr, b_hz, b_hn,
                                   wsGi, wsH, wsC, out);
}